// Round 1
// baseline (4056.922 us; speedup 1.0000x reference)
//
#include <hip/hip_runtime.h>
#include <hip/hip_fp16.h>
#include <stdint.h>

// GRU encoder: B=512, T=512, H=256, IN=2.
// Strategy (round 0): persistent per-block recurrence. Each block owns 2
// batches, h[2][256] fp32 in LDS, streams W_hh every step from L2 as fp16
// (packed/transposed by a prep kernel into d_ws for coalesced access).
// Thread t owns element i=t and computes full dot products for gate rows
// {t, 256+t, 512+t} (no cross-thread reduction needed).

#define BB 512
#define TT 512
#define HH 256
#define G3 768   // 3*H
#define K2 128   // H/2 (fp16 pairs along k)

// Pack W_hh [768][256] fp32 -> Wq fp16 pairs, layout: dword index
// (k2*256 + i)*3 + j  holds half2( W[(j*256+i)][2*k2], W[(j*256+i)][2*k2+1] ).
// So in the main loop, lane t reads 3 consecutive dwords at k2*768 + 3*t:
// 64 lanes x 12 B contiguous -> fully coalesced.
__global__ void prep_pack(const float* __restrict__ Whh, uint32_t* __restrict__ Wq) {
    int n = blockIdx.x * blockDim.x + threadIdx.x;   // [0, 98304)
    int k2   = n & (K2 - 1);
    int rest = n >> 7;            // [0, 768)
    int i = rest & (HH - 1);      // element index
    int j = rest >> 8;            // gate 0..2 (r,z,n)
    int g = j * HH + i;           // row in W_hh
    float2 w = *(const float2*)(Whh + g * HH + 2 * k2);   // coalesced 8B/lane
    __half2 hw = __floats2half2_rn(w.x, w.y);
    Wq[(k2 * HH + i) * 3 + j] = *(uint32_t*)&hw;
}

__global__ void __launch_bounds__(256)
gru_persist(const float* __restrict__ x,        // [B,T,2]
            const int* __restrict__ len,        // [B]
            const float* __restrict__ h0,       // [B,H]
            const float* __restrict__ Wih,      // [768,2]
            const float* __restrict__ bih,      // [768]
            const float* __restrict__ bhh,      // [768]
            const uint32_t* __restrict__ Wq,    // packed fp16 W_hh
            float* __restrict__ out)            // [B,H]
{
    __shared__ float hsh[2][HH];
    const int t  = threadIdx.x;          // 0..255 = element index
    const int b0 = blockIdx.x * 2;
    const int b1 = b0 + 1;

    hsh[0][t] = h0[b0 * HH + t];
    hsh[1][t] = h0[b1 * HH + t];

    const int gR = t, gZ = HH + t, gN = 2 * HH + t;
    const float wR0 = Wih[2 * gR], wR1 = Wih[2 * gR + 1];
    const float wZ0 = Wih[2 * gZ], wZ1 = Wih[2 * gZ + 1];
    const float wN0 = Wih[2 * gN], wN1 = Wih[2 * gN + 1];
    const float cR = bih[gR] + bhh[gR];   // r: biases combine
    const float cZ = bih[gZ] + bhh[gZ];   // z: biases combine
    const float cN = bih[gN];             // n: b_ih outside r*( )
    const float dN = bhh[gN];             // n: b_hh inside  r*( )
    const int l0 = len[b0];
    const int l1 = len[b1];
    const float* xb0 = x + (size_t)b0 * TT * 2;
    const float* xb1 = x + (size_t)b1 * TT * 2;

    __syncthreads();

    for (int s = 0; s < TT; ++s) {
        // input projections (broadcast global reads, L1-hit)
        const float x00 = xb0[2 * s], x01 = xb0[2 * s + 1];
        const float x10 = xb1[2 * s], x11 = xb1[2 * s + 1];

        float aR0 = 0.f, aZ0 = 0.f, aN0 = 0.f;
        float aR1 = 0.f, aZ1 = 0.f, aN1 = 0.f;

        const uint32_t* wp = Wq + t * 3;
        #pragma unroll 8
        for (int k = 0; k < K2; ++k) {
            const uint3 w3 = *(const uint3*)wp;   // 12B/lane, wave-contiguous
            wp += G3;
            const float2 fR = __half22float2(*(const __half2*)&w3.x);
            const float2 fZ = __half22float2(*(const __half2*)&w3.y);
            const float2 fN = __half22float2(*(const __half2*)&w3.z);
            const float2 hv0 = *(const float2*)&hsh[0][2 * k];  // LDS broadcast
            const float2 hv1 = *(const float2*)&hsh[1][2 * k];
            aR0 = fmaf(fR.x, hv0.x, fmaf(fR.y, hv0.y, aR0));
            aZ0 = fmaf(fZ.x, hv0.x, fmaf(fZ.y, hv0.y, aZ0));
            aN0 = fmaf(fN.x, hv0.x, fmaf(fN.y, hv0.y, aN0));
            aR1 = fmaf(fR.x, hv1.x, fmaf(fR.y, hv1.y, aR1));
            aZ1 = fmaf(fZ.x, hv1.x, fmaf(fZ.y, hv1.y, aZ1));
            aN1 = fmaf(fN.x, hv1.x, fmaf(fN.y, hv1.y, aN1));
        }

        // gates, batch 0
        const float sR0 = aR0 + fmaf(x00, wR0, fmaf(x01, wR1, cR));
        const float sZ0 = aZ0 + fmaf(x00, wZ0, fmaf(x01, wZ1, cZ));
        const float r0 = 1.f / (1.f + __expf(-sR0));
        const float z0 = 1.f / (1.f + __expf(-sZ0));
        const float n0 = tanhf(fmaf(x00, wN0, fmaf(x01, wN1, cN)) + r0 * (aN0 + dN));
        // gates, batch 1
        const float sR1 = aR1 + fmaf(x10, wR0, fmaf(x11, wR1, cR));
        const float sZ1 = aZ1 + fmaf(x10, wZ0, fmaf(x11, wZ1, cZ));
        const float r1 = 1.f / (1.f + __expf(-sR1));
        const float z1 = 1.f / (1.f + __expf(-sZ1));
        const float n1 = tanhf(fmaf(x10, wN0, fmaf(x11, wN1, cN)) + r1 * (aN1 + dN));

        const float hp0 = hsh[0][t];
        const float hp1 = hsh[1][t];
        const float hn0 = fmaf(z0, hp0 - n0, n0);   // (1-z)n + z h
        const float hn1 = fmaf(z1, hp1 - n1, n1);

        __syncthreads();              // all k-loop reads of h done
        hsh[0][t] = hn0;
        hsh[1][t] = hn1;
        if (s == l0 - 1) out[b0 * HH + t] = hn0;
        if (s == l1 - 1) out[b1 * HH + t] = hn1;
        __syncthreads();              // h_new visible for next step
    }
}

extern "C" void kernel_launch(void* const* d_in, const int* in_sizes, int n_in,
                              void* d_out, int out_size, void* d_ws, size_t ws_size,
                              hipStream_t stream) {
    const float* x    = (const float*)d_in[0];
    const int*   lenp = (const int*)d_in[1];     // jax default x64 off -> int32
    const float* h0   = (const float*)d_in[2];
    const float* Wih  = (const float*)d_in[3];
    const float* Whh  = (const float*)d_in[4];
    const float* bih  = (const float*)d_in[5];
    const float* bhh  = (const float*)d_in[6];
    float* out = (float*)d_out;

    uint32_t* Wq = (uint32_t*)d_ws;   // needs 384 KB scratch

    prep_pack<<<G3 * K2 / 256, 256, 0, stream>>>(Whh, Wq);
    gru_persist<<<BB / 2, 256, 0, stream>>>(x, lenp, h0, Wih, bih, bhh, Wq, out);
}

// Round 2
// 2004.264 us; speedup vs baseline: 2.0241x; 2.0241x over previous
//
#include <hip/hip_runtime.h>
#include <stdint.h>

// GRU encoder: B=512, T=512, H=256, IN=2.
// R1 strategy: register-resident fp16 W_hh (384 VGPRs/thread), v_dot2_f32_f16
// inner loop, h fp32 master in registers + fp16 mirror in LDS (broadcast
// reads). 256 persistent blocks x 256 threads, 2 batches/block, per-batch
// early exit. Eliminates the 24.8 TB/s L2 W-streaming that bound R0.

typedef _Float16 half2_t __attribute__((ext_vector_type(2)));

#define BB 512
#define TT 512
#define HH 256
#define G3 768
#define K2 128   // half2 pairs along K
#define Q4 32    // uint4 groups along K (4 half2 = 8 halves each)

__device__ __forceinline__ float fdot2(half2_t a, half2_t b, float c) {
#if __has_builtin(__builtin_amdgcn_fdot2)
    return __builtin_amdgcn_fdot2(a, b, c, false);
#else
    return fmaf((float)a.x, (float)b.x, fmaf((float)a.y, (float)b.y, c));
#endif
}

// Wq4[(g*Q4 + q)*HH + i] = 8 halves of W_hh[g*256 + i][8q .. 8q+7]
__global__ void prep_pack(const float* __restrict__ Whh, uint4* __restrict__ Wq4) {
    int n = blockIdx.x * blockDim.x + threadIdx.x;   // [0, 24576)
    int i = n & (HH - 1);
    int rest = n >> 8;           // [0, 96)
    int q = rest & (Q4 - 1);
    int g = rest >> 5;
    const float* src = Whh + ((size_t)(g * HH + i)) * HH + 8 * q;
    uint4 o;
    o.x = __builtin_bit_cast(uint32_t, half2_t{(_Float16)src[0], (_Float16)src[1]});
    o.y = __builtin_bit_cast(uint32_t, half2_t{(_Float16)src[2], (_Float16)src[3]});
    o.z = __builtin_bit_cast(uint32_t, half2_t{(_Float16)src[4], (_Float16)src[5]});
    o.w = __builtin_bit_cast(uint32_t, half2_t{(_Float16)src[6], (_Float16)src[7]});
    Wq4[(g * Q4 + q) * HH + i] = o;
}

__device__ __forceinline__ float sigmoid_f(float x) {
    return __builtin_amdgcn_rcpf(1.f + __expf(-x));
}
__device__ __forceinline__ float tanh_f(float x) {
    x = fminf(fmaxf(x, -15.f), 15.f);
    float e = __expf(-2.f * x);
    return (1.f - e) * __builtin_amdgcn_rcpf(1.f + e);
}

__global__ void __launch_bounds__(256, 1)
gru_persist(const float* __restrict__ x,        // [B,T,2]
            const int* __restrict__ len,        // [B] (int32 confirmed R0)
            const float* __restrict__ h0,       // [B,H]
            const float* __restrict__ Wih,      // [768,2]
            const float* __restrict__ bih,      // [768]
            const float* __restrict__ bhh,      // [768]
            const uint4* __restrict__ Wq4,      // packed fp16 W_hh
            float* __restrict__ out)            // [B,H]
{
    __shared__ __align__(16) _Float16 hsh[2][HH];
    const int t  = threadIdx.x;
    const int b0 = blockIdx.x * 2;
    const int b1 = b0 + 1;

    // ---- load W_hh rows {t, 256+t, 512+t} into registers: 384 VGPRs ----
    half2_t wv[3][K2];
    #pragma unroll
    for (int g = 0; g < 3; ++g) {
        #pragma unroll
        for (int q = 0; q < Q4; ++q) {
            const uint4 u = Wq4[(g * Q4 + q) * HH + t];   // lane-contiguous 16B
            wv[g][4*q+0] = __builtin_bit_cast(half2_t, u.x);
            wv[g][4*q+1] = __builtin_bit_cast(half2_t, u.y);
            wv[g][4*q+2] = __builtin_bit_cast(half2_t, u.z);
            wv[g][4*q+3] = __builtin_bit_cast(half2_t, u.w);
        }
    }

    float hp0 = h0[b0 * HH + t];
    float hp1 = h0[b1 * HH + t];
    hsh[0][t] = (_Float16)hp0;
    hsh[1][t] = (_Float16)hp1;

    const int gR = t, gZ = HH + t, gN = 2 * HH + t;
    const float wR0 = Wih[2*gR], wR1 = Wih[2*gR+1];
    const float wZ0 = Wih[2*gZ], wZ1 = Wih[2*gZ+1];
    const float wN0 = Wih[2*gN], wN1 = Wih[2*gN+1];
    const float cR = bih[gR] + bhh[gR];
    const float cZ = bih[gZ] + bhh[gZ];
    const float cN = bih[gN];
    const float dN = bhh[gN];
    const int l0 = len[b0];
    const int l1 = len[b1];
    const int lmax = l0 > l1 ? l0 : l1;
    const float* xb0 = x + (size_t)b0 * TT * 2;
    const float* xb1 = x + (size_t)b1 * TT * 2;

    __syncthreads();

    #pragma unroll 1
    for (int s = 0; s < lmax; ++s) {
        float hn0 = 0.f, hn1 = 0.f;

        if (s < l0) {
            const float x0 = xb0[2*s], x1 = xb0[2*s+1];
            float aR = 0.f, aZ = 0.f, aN = 0.f;
            const float4* hp = (const float4*)hsh[0];
            #pragma unroll
            for (int q = 0; q < Q4; ++q) {
                const float4 hv = hp[q];                  // ds_read_b128 broadcast
                const half2_t hA = __builtin_bit_cast(half2_t, hv.x);
                const half2_t hB = __builtin_bit_cast(half2_t, hv.y);
                const half2_t hC = __builtin_bit_cast(half2_t, hv.z);
                const half2_t hD = __builtin_bit_cast(half2_t, hv.w);
                aR = fdot2(wv[0][4*q+0], hA, aR);
                aZ = fdot2(wv[1][4*q+0], hA, aZ);
                aN = fdot2(wv[2][4*q+0], hA, aN);
                aR = fdot2(wv[0][4*q+1], hB, aR);
                aZ = fdot2(wv[1][4*q+1], hB, aZ);
                aN = fdot2(wv[2][4*q+1], hB, aN);
                aR = fdot2(wv[0][4*q+2], hC, aR);
                aZ = fdot2(wv[1][4*q+2], hC, aZ);
                aN = fdot2(wv[2][4*q+2], hC, aN);
                aR = fdot2(wv[0][4*q+3], hD, aR);
                aZ = fdot2(wv[1][4*q+3], hD, aZ);
                aN = fdot2(wv[2][4*q+3], hD, aN);
            }
            const float r = sigmoid_f(aR + fmaf(x0, wR0, fmaf(x1, wR1, cR)));
            const float z = sigmoid_f(aZ + fmaf(x0, wZ0, fmaf(x1, wZ1, cZ)));
            const float n = tanh_f(fmaf(x0, wN0, fmaf(x1, wN1, cN)) + r * (aN + dN));
            hn0 = fmaf(z, hp0 - n, n);
        }
        if (s < l1) {
            const float x0 = xb1[2*s], x1 = xb1[2*s+1];
            float aR = 0.f, aZ = 0.f, aN = 0.f;
            const float4* hp = (const float4*)hsh[1];
            #pragma unroll
            for (int q = 0; q < Q4; ++q) {
                const float4 hv = hp[q];
                const half2_t hA = __builtin_bit_cast(half2_t, hv.x);
                const half2_t hB = __builtin_bit_cast(half2_t, hv.y);
                const half2_t hC = __builtin_bit_cast(half2_t, hv.z);
                const half2_t hD = __builtin_bit_cast(half2_t, hv.w);
                aR = fdot2(wv[0][4*q+0], hA, aR);
                aZ = fdot2(wv[1][4*q+0], hA, aZ);
                aN = fdot2(wv[2][4*q+0], hA, aN);
                aR = fdot2(wv[0][4*q+1], hB, aR);
                aZ = fdot2(wv[1][4*q+1], hB, aZ);
                aN = fdot2(wv[2][4*q+1], hB, aN);
                aR = fdot2(wv[0][4*q+2], hC, aR);
                aZ = fdot2(wv[1][4*q+2], hC, aZ);
                aN = fdot2(wv[2][4*q+2], hC, aN);
                aR = fdot2(wv[0][4*q+3], hD, aR);
                aZ = fdot2(wv[1][4*q+3], hD, aZ);
                aN = fdot2(wv[2][4*q+3], hD, aN);
            }
            const float r = sigmoid_f(aR + fmaf(x0, wR0, fmaf(x1, wR1, cR)));
            const float z = sigmoid_f(aZ + fmaf(x0, wZ0, fmaf(x1, wZ1, cZ)));
            const float n = tanh_f(fmaf(x0, wN0, fmaf(x1, wN1, cN)) + r * (aN + dN));
            hn1 = fmaf(z, hp1 - n, n);
        }

        __syncthreads();               // all reads of hsh done
        if (s < l0) {
            hsh[0][t] = (_Float16)hn0;
            hp0 = hn0;
            if (s == l0 - 1) out[b0 * HH + t] = hn0;
        }
        if (s < l1) {
            hsh[1][t] = (_Float16)hn1;
            hp1 = hn1;
            if (s == l1 - 1) out[b1 * HH + t] = hn1;
        }
        __syncthreads();               // h_new visible before next step
    }
}

extern "C" void kernel_launch(void* const* d_in, const int* in_sizes, int n_in,
                              void* d_out, int out_size, void* d_ws, size_t ws_size,
                              hipStream_t stream) {
    const float* x    = (const float*)d_in[0];
    const int*   lenp = (const int*)d_in[1];
    const float* h0   = (const float*)d_in[2];
    const float* Wih  = (const float*)d_in[3];
    const float* Whh  = (const float*)d_in[4];
    const float* bih  = (const float*)d_in[5];
    const float* bhh  = (const float*)d_in[6];
    float* out = (float*)d_out;

    uint4* Wq4 = (uint4*)d_ws;   // 384 KB scratch

    prep_pack<<<G3 * Q4 / 256, 256, 0, stream>>>(Whh, Wq4);
    gru_persist<<<BB / 2, 256, 0, stream>>>(x, lenp, h0, Wih, bih, bhh, Wq4, out);
}